// Round 13
// baseline (160.075 us; speedup 1.0000x reference)
//
#include <hip/hip_runtime.h>
#include <hip/hip_fp16.h>

// ---------------------------------------------------------------------------
// B=8, N=1024, F=320, H=5 (heads collapse: at = (Q·K^T)/8)
// R13: split-K=4 for G4' (was 160 blocks = 0.625/CU, 32 serial latency-bound
//      K-iters -> now 640 blocks = 2.5/CU, 8 iters each) with fp32 atomicAdd
//      partials. prep_all pre-fills out with bias (ordering guaranteed by
//      same-stream dispatch order). Everything else identical to R12.
// Pipeline:
//   prep_all:    h->fp16 | Wqk^T | weight^T | out=bias (one launch)
//   g1_combined: [hWT = wTp @ h16^T] + [Q,K = h16 @ WqkT^T + bqk], 512 blocks
//   G2  (128x128 dbuf): at = 0.125 * Q@K^T -> fp16
//   topk_softmax: exact 171st-largest (2-pass radix, 16-bit keys) -> attn fp16
//   G4' (256x64 dbuf, split-K=4, grid (5,16,8)): out += attn @ hWT^T (atomic)
// ---------------------------------------------------------------------------

typedef __attribute__((ext_vector_type(8))) _Float16 half8;
typedef __attribute__((ext_vector_type(4))) float f32x4;

// ---- stage a (nrow16*16) x 32 fp16 tile into LDS, K-chunk XOR-swizzled -----
// LDS slot s of row r holds global chunk s ^ ((r>>1)&3). global_load_lds dest
// is the mandatory uniform base + lane*16B; only the global SOURCE is
// permuted (stays 64B coalesced).
__device__ __forceinline__ void stage_tile(const __half* g, __half* lds,
                                           int nrow16, int ld, int wave, int lane) {
    const int r = lane >> 2;
    const int c = ((lane & 3) ^ ((lane >> 3) & 3)) * 8;  // swizzled chunk
    for (int i = wave; i < nrow16; i += 4) {
        const __half* src = g + (long)(i * 16 + r) * ld + c;
        __builtin_amdgcn_global_load_lds(
            (const __attribute__((address_space(1))) unsigned int*)src,
            (__attribute__((address_space(3))) unsigned int*)(lds + i * 512),
            16, 0, 0);
    }
}

// ---------------------------------------------------------------------------
// NT fp16 MFMA GEMM, double-buffered.
// 256 threads = 4 waves in WM x WN grid; wave tile 64x64 (16 MFMA/K-step).
// EPI: 1 = +bqk, deinterleave -> Q fp16, K fp16   [G1']
//      2 = fp16 store                              [hWT]
//      4 = fp16 store (alpha)                      [G2 -> at]
//      5 = fp32 atomicAdd, split-K=4 (y = ytile*4+split)  [G4' -> out]
// ---------------------------------------------------------------------------
template <int WM, int WN, int EPI>
__global__ __launch_bounds__(256) void gemm_nt(
    const __half* __restrict__ A, const __half* __restrict__ B,
    void* __restrict__ C, void* __restrict__ C2,
    const float* __restrict__ bias,
    int K, int lda, int ldb, int ldc,
    long sA, long sB, long sC, float alpha)
{
    constexpr int BM = WM * 64;
    constexpr int BN = WN * 64;
    constexpr int BUF = BM * 32 + BN * 32;
    __shared__ __half smem[2 * BUF];

    const int tid  = threadIdx.x;
    const int lane = tid & 63;
    const int wave = tid >> 6;
    const int wm   = wave / WN;
    const int wn   = wave % WN;
    const int bz   = blockIdx.z;

    int by = blockIdx.y;
    int ks = 0;                 // split-K index (EPI 5 only)
    int nIter = K >> 5;
    if (EPI == 5) {
        ks = by & 3;
        by >>= 2;
        nIter = K >> 7;         // K/4 per split, 32 per iter
    }
    const int kOff = (EPI == 5) ? ks * (K >> 2) : 0;

    const __half* Ab = A + bz * sA + (long)by * BM * lda + kOff;
    const __half* Bb = B + bz * sB + (long)blockIdx.x * BN * ldb + kOff;

    f32x4 acc[4][4];
    #pragma unroll
    for (int i = 0; i < 4; ++i)
        #pragma unroll
        for (int j = 0; j < 4; ++j) acc[i][j] = (f32x4){0.f, 0.f, 0.f, 0.f};

    const int lrow = lane & 15;
    const int quad = lane >> 4;
    const int swz = (quad ^ ((lrow >> 1) & 3)) * 8;

    stage_tile(Ab, smem, BM / 16, lda, wave, lane);
    stage_tile(Bb, smem + BM * 32, BN / 16, ldb, wave, lane);

    for (int it = 0; it < nIter; ++it) {
        __syncthreads();
        if (it + 1 < nIter) {
            __half* nb = smem + ((it + 1) & 1) * BUF;
            const int k1 = (it + 1) << 5;
            stage_tile(Ab + k1, nb, BM / 16, lda, wave, lane);
            stage_tile(Bb + k1, nb + BM * 32, BN / 16, ldb, wave, lane);
        }
        const __half* buf = smem + (it & 1) * BUF;
        const __half* pA = buf + (wm * 64 + lrow) * 32 + swz;
        const __half* pB = buf + BM * 32 + (wn * 64 + lrow) * 32 + swz;
        half8 ah[4], bh[4];
        #pragma unroll
        for (int mt = 0; mt < 4; ++mt) ah[mt] = *(const half8*)(pA + mt * 512);
        #pragma unroll
        for (int nt = 0; nt < 4; ++nt) bh[nt] = *(const half8*)(pB + nt * 512);
        #pragma unroll
        for (int mt = 0; mt < 4; ++mt)
            #pragma unroll
            for (int nt = 0; nt < 4; ++nt)
                acc[mt][nt] = __builtin_amdgcn_mfma_f32_16x16x32_f16(
                    ah[mt], bh[nt], acc[mt][nt], 0, 0, 0);
    }

    const int row_base = by * BM + wm * 64;
    const int col_base = blockIdx.x * BN + wn * 64;
    #pragma unroll
    for (int mt = 0; mt < 4; ++mt)
        #pragma unroll
        for (int nt = 0; nt < 4; ++nt)
            #pragma unroll
            for (int r = 0; r < 4; ++r) {
                const int row = row_base + mt * 16 + quad * 4 + r;
                const int col = col_base + nt * 16 + lrow;
                const float v = acc[mt][nt][r];
                if (EPI == 1) {
                    const float val = v + bias[col];
                    const long idx = (long)row * 320 + (col >> 1);
                    if (col & 1) ((__half*)C2)[idx] = __float2half(val);
                    else         ((__half*)C)[idx]  = __float2half(val);
                } else if (EPI == 2) {
                    ((__half*)C)[(long)row * ldc + col] = __float2half(v);
                } else if (EPI == 4) {
                    ((__half*)C)[bz * sC + (long)row * ldc + col] =
                        __float2half(alpha * v);
                } else {  // EPI == 5: split-K partial, out pre-filled with bias
                    atomicAdd(&((float*)C)[bz * sC + (long)row * ldc + col], v);
                }
            }
}

// ---------------------------------------------------------------------------
// 128x128 NT fp16 dbuf GEMM body with runtime bx/by (R10-proven), K=320.
// EPI 1: +bqk, deinterleave -> Q,K fp16.  EPI 2: fp16 store (hWT, ldc=8192).
// ---------------------------------------------------------------------------
template <int EPI>
__device__ __forceinline__ void gemm_body(
    const __half* __restrict__ A, const __half* __restrict__ B,
    void* __restrict__ C, void* __restrict__ C2, const float* __restrict__ bias,
    int lda, int ldb, int ldc, int bx, int by, __half* smem)
{
    constexpr int BUF = 8192;
    const int tid  = threadIdx.x;
    const int lane = tid & 63;
    const int wave = tid >> 6;
    const int wm   = wave >> 1;
    const int wn   = wave & 1;

    const __half* Ab = A + (long)by * 128 * lda;
    const __half* Bb = B + (long)bx * 128 * ldb;

    f32x4 acc[4][4];
    #pragma unroll
    for (int i = 0; i < 4; ++i)
        #pragma unroll
        for (int j = 0; j < 4; ++j) acc[i][j] = (f32x4){0.f, 0.f, 0.f, 0.f};

    const int lrow = lane & 15;
    const int quad = lane >> 4;
    const int swz = (quad ^ ((lrow >> 1) & 3)) * 8;

    stage_tile(Ab, smem, 8, lda, wave, lane);
    stage_tile(Bb, smem + 4096, 8, ldb, wave, lane);

    for (int it = 0; it < 10; ++it) {
        __syncthreads();
        if (it + 1 < 10) {
            __half* nb = smem + ((it + 1) & 1) * BUF;
            stage_tile(Ab + (it + 1) * 32, nb, 8, lda, wave, lane);
            stage_tile(Bb + (it + 1) * 32, nb + 4096, 8, ldb, wave, lane);
        }
        const __half* buf = smem + (it & 1) * BUF;
        const __half* pA = buf + (wm * 64 + lrow) * 32 + swz;
        const __half* pB = buf + 4096 + (wn * 64 + lrow) * 32 + swz;
        half8 ah[4], bh[4];
        #pragma unroll
        for (int mt = 0; mt < 4; ++mt) ah[mt] = *(const half8*)(pA + mt * 512);
        #pragma unroll
        for (int nt = 0; nt < 4; ++nt) bh[nt] = *(const half8*)(pB + nt * 512);
        #pragma unroll
        for (int mt = 0; mt < 4; ++mt)
            #pragma unroll
            for (int nt = 0; nt < 4; ++nt)
                acc[mt][nt] = __builtin_amdgcn_mfma_f32_16x16x32_f16(
                    ah[mt], bh[nt], acc[mt][nt], 0, 0, 0);
    }

    const int row_base = by * 128 + wm * 64;
    const int col_base = bx * 128 + wn * 64;
    #pragma unroll
    for (int mt = 0; mt < 4; ++mt)
        #pragma unroll
        for (int nt = 0; nt < 4; ++nt)
            #pragma unroll
            for (int r = 0; r < 4; ++r) {
                const int row = row_base + mt * 16 + quad * 4 + r;
                const int col = col_base + nt * 16 + lrow;
                const float v = acc[mt][nt][r];
                if (EPI == 1) {
                    const float val = v + bias[col];
                    const long idx = (long)row * 320 + (col >> 1);
                    if (col & 1) ((__half*)C2)[idx] = __float2half(val);
                    else         ((__half*)C)[idx]  = __float2half(val);
                } else {
                    ((__half*)C)[(long)row * ldc + col] = __float2half(v);
                }
            }
}

// ---- combined: blocks 0..191 do hWT (64x3 tiles); 192..511 do G1' (5x64) ---
__global__ __launch_bounds__(256) void g1_combined(
    const __half* __restrict__ h16, const __half* __restrict__ wTp,
    const __half* __restrict__ WqkT, __half* __restrict__ hWT,
    __half* __restrict__ Q, __half* __restrict__ Kb,
    const float* __restrict__ bqk)
{
    __shared__ __half smem[2 * 8192];
    const int bx = blockIdx.x;
    if (bx < 192) {
        gemm_body<2>(wTp, h16, hWT, nullptr, nullptr,
                     320, 320, 8192, bx % 64, bx / 64, smem);
    } else {
        const int b = bx - 192;
        gemm_body<1>(h16, WqkT, Q, Kb, bqk,
                     320, 320, 320, b % 5, b / 5, smem);
    }
}

// ---- fused prep: h->fp16 (0..2559) | Wqk^T | weight^T | out=bias (2860..) --
__global__ __launch_bounds__(256) void prep_all(
    const float* __restrict__ h, ushort4* __restrict__ h16,
    const float* __restrict__ Wqk, __half* __restrict__ WqkT,
    const float* __restrict__ weight, __half* __restrict__ wTp,
    const float* __restrict__ bias, float4* __restrict__ out4)
{
    const int bx = blockIdx.x;
    if (bx < 2560) {
        const int i = bx * 256 + threadIdx.x;
        const float4 v = ((const float4*)h)[i];
        ushort4 o;
        o.x = __half_as_ushort(__float2half(v.x));
        o.y = __half_as_ushort(__float2half(v.y));
        o.z = __half_as_ushort(__float2half(v.z));
        o.w = __half_as_ushort(__float2half(v.w));
        h16[i] = o;
        return;
    }
    if (bx >= 2860) {
        // out pre-fill with bias: out[row][col] = bias[col]; float4 layout,
        // 320 floats/row = 80 float4/row.
        const int i = (bx - 2860) * 256 + threadIdx.x;   // 655360 total
        out4[i] = ((const float4*)bias)[i % 80];
        return;
    }
    __shared__ float t[32][33];
    const float* src;
    __half* dst;
    int ldS, ldT, c0, r0;
    if (bx < 2760) {
        const int b = bx - 2560;
        src = Wqk; dst = WqkT; ldS = 640; ldT = 320;
        c0 = (b % 20) * 32; r0 = (b / 20) * 32;
    } else {
        const int b = bx - 2760;
        src = weight; dst = wTp; ldS = 320; ldT = 320;
        c0 = (b % 10) * 32; r0 = (b / 10) * 32;
    }
    const int lx = threadIdx.x & 31, ly = threadIdx.x >> 5;
    #pragma unroll
    for (int i = 0; i < 4; ++i)
        t[ly + 8 * i][lx] = src[(long)(r0 + ly + 8 * i) * ldS + c0 + lx];
    __syncthreads();
    #pragma unroll
    for (int i = 0; i < 4; ++i)
        dst[(long)(c0 + ly + 8 * i) * ldT + r0 + lx] = __float2half(t[lx][ly + 8 * i]);
}

// ---------------------------------------------------------------------------
// Exact 171st-largest per row of 1024 fp16 values: 2-pass radix select on
// 16-bit order-preserving keys. One wave per row (4 rows / block).
// ---------------------------------------------------------------------------
__global__ __launch_bounds__(256) void topk_softmax(const __half* __restrict__ at,
                                                    __half* __restrict__ attn)
{
    __shared__ int hist[4][256];
    const int lane = threadIdx.x & 63;
    const int wave = threadIdx.x >> 6;
    const long row = (long)blockIdx.x * 4 + wave;

    unsigned short vs[16];
    {
        const uint4* p = (const uint4*)(at + row * 1024 + lane * 16);
        *(uint4*)&vs[0] = p[0];
        *(uint4*)&vs[8] = p[1];
    }

    unsigned key[16];
    #pragma unroll
    for (int i = 0; i < 16; ++i) {
        const unsigned u = vs[i];
        key[i] = (u & 0x8000u) ? ((~u) & 0xFFFFu) : (u | 0x8000u);
    }

    unsigned prefix = 0, pmask = 0;
    int kk = 171;

    #pragma unroll
    for (int pass = 0; pass < 2; ++pass) {
        const int shift = 8 - 8 * pass;
        *(int4*)&hist[wave][lane * 4] = make_int4(0, 0, 0, 0);
        __syncthreads();
        #pragma unroll
        for (int i = 0; i < 16; ++i) {
            if ((key[i] & pmask) == prefix)
                atomicAdd(&hist[wave][(key[i] >> shift) & 255], 1);
        }
        __syncthreads();
        const int4 hh = *(const int4*)&hist[wave][lane * 4];
        const int s = hh.x + hh.y + hh.z + hh.w;
        int suf = s;
        #pragma unroll
        for (int off = 1; off < 64; off <<= 1) {
            const int o = __shfl_down(suf, off);
            if (lane + off < 64) suf += o;
        }
        const int cgt3 = suf - s;
        const int cgt2 = cgt3 + hh.w;
        const int cgt1 = cgt2 + hh.z;
        const int cgt0 = cgt1 + hh.y;
        int pick = 0x7FFFFFFF;
        if (cgt3 < kk && kk <= cgt3 + hh.w) pick = ((4 * lane + 3) << 16) | (kk - cgt3);
        if (cgt2 < kk && kk <= cgt2 + hh.z) pick = ((4 * lane + 2) << 16) | (kk - cgt2);
        if (cgt1 < kk && kk <= cgt1 + hh.y) pick = ((4 * lane + 1) << 16) | (kk - cgt1);
        if (cgt0 < kk && kk <= cgt0 + hh.x) pick = ((4 * lane + 0) << 16) | (kk - cgt0);
        #pragma unroll
        for (int off = 32; off > 0; off >>= 1) pick = min(pick, __shfl_xor(pick, off));
        const unsigned digit = (unsigned)(pick >> 16);
        kk = pick & 0xFFFF;
        prefix |= digit << shift;
        pmask  |= 0xFFu << shift;
        if (pass == 0) __syncthreads();
    }

    const unsigned short tu = (prefix & 0x8000u) ? (unsigned short)(prefix & 0x7FFFu)
                                                 : (unsigned short)((~prefix) & 0xFFFFu);
    const float thr = __half2float(__ushort_as_half(tu));

    float lg[16];
    float mx = -3.4e38f;
    #pragma unroll
    for (int i = 0; i < 16; ++i) {
        const float v = __half2float(__ushort_as_half(vs[i]));
        const float a = (v < thr) ? -1e-7f : v;
        lg[i] = a * (1.0f / 0.3f);
        mx = fmaxf(mx, lg[i]);
    }
    #pragma unroll
    for (int off = 32; off > 0; off >>= 1) mx = fmaxf(mx, __shfl_xor(mx, off));

    float e[16];
    float sum = 0.f;
    #pragma unroll
    for (int i = 0; i < 16; ++i) { e[i] = __expf(lg[i] - mx); sum += e[i]; }
    #pragma unroll
    for (int off = 32; off > 0; off >>= 1) sum += __shfl_xor(sum, off);
    const float inv = 1.0f / sum;

    unsigned short os[16];
    #pragma unroll
    for (int i = 0; i < 16; ++i) os[i] = __half_as_ushort(__float2half(e[i] * inv));
    uint4* q = (uint4*)(attn + row * 1024 + lane * 16);
    q[0] = *(const uint4*)&os[0];
    q[1] = *(const uint4*)&os[8];
}

extern "C" void kernel_launch(void* const* d_in, const int* in_sizes, int n_in,
                              void* d_out, int out_size, void* d_ws, size_t ws_size,
                              hipStream_t stream) {
    (void)in_sizes; (void)n_in; (void)out_size; (void)ws_size;

    const float* h      = (const float*)d_in[0];  // 8x1024x320
    const float* Wqk    = (const float*)d_in[1];  // 320x640
    const float* bqk    = (const float*)d_in[2];  // 640
    const float* weight = (const float*)d_in[3];  // 320x320
    const float* bias   = (const float*)d_in[4];  // 320
    float* out = (float*)d_out;                   // 8192x320

    // workspace layout
    char* p = (char*)d_ws;
    __half* at   = (__half*)p; p += 8388608L * 2;        // 16 MB
    __half* attn = (__half*)p; p += 8388608L * 2;        // 16 MB
    __half* h16  = (__half*)p; p += 2621440L * 2;        // 5 MB
    __half* Q    = (__half*)p; p += 2621440L * 2;        // 5 MB
    __half* Kb   = (__half*)p; p += 2621440L * 2;        // 5 MB
    __half* WqkT = (__half*)p; p += 640L * 320 * 2;      // 400 KB
    __half* wTp  = (__half*)p; p += 384L * 320 * 2;      // padded to 384 rows
    __half* hWT  = (__half*)p; p += 384L * 8192 * 2;     // 6 MB (incl pad rows)

    // --- prep (1 launch): h->fp16, WqkT, wTp, out=bias ---
    prep_all<<<5420, 256, 0, stream>>>(h, (ushort4*)h16, Wqk, WqkT, weight, wTp,
                                       bias, (float4*)out);

    // --- combined: hWT (192 blocks) + G1' Q/K (320 blocks) ---
    g1_combined<<<512, 256, 0, stream>>>(h16, wTp, WqkT, hWT, Q, Kb, bqk);

    // --- G2: at = 0.125 * Q@K^T (fp16 out), 128x128 dbuf ---
    gemm_nt<2, 2, 4><<<dim3(8, 8, 8), 256, 0, stream>>>(
        Q, Kb, at, nullptr, nullptr,
        320, 320, 320, 1024, 327680, 327680, 1048576, 0.125f);

    // --- topk + softmax -> attn (fp16); one wave per row ---
    topk_softmax<<<2048, 256, 0, stream>>>(at, attn);

    // --- G4': out += attn @ hWT^T (split-K=4, atomic; out pre-filled w/ bias)
    gemm_nt<4, 1, 5><<<dim3(5, 16, 8), 256, 0, stream>>>(
        attn, hWT, out, nullptr, nullptr,
        1024, 1024, 8192, 320, 1048576, 1024, 327680, 1.0f);
}

// Round 14
// 134.490 us; speedup vs baseline: 1.1902x; 1.1902x over previous
//
#include <hip/hip_runtime.h>
#include <hip/hip_fp16.h>

// ---------------------------------------------------------------------------
// B=8, N=1024, F=320, H=5 (heads collapse: at = (Q·K^T)/8)
// R14: revert R13's split-K atomics (47 µs, atomic-epilogue-bound regression).
//      = R12 (best, 138.4 µs) + G4' BK=64: two 32-wide sub-tiles per barrier
//      round (nIter 32->16). G4' is grid-limited (160 blk = 0.625/CU), so
//      wall ~ nIter x staging latency; LDS 80 KB is free here. Numerics
//      bit-identical (same k-order, same layouts) -> absmax 0.03125.
// Pipeline:
//   prep_all:    h->fp16 | Wqk^T | weight^T (one launch)
//   g1_combined: [hWT = wTp @ h16^T] + [Q,K = h16 @ WqkT^T + bqk], 512 blocks
//   G2  (128x128 dbuf, CH=1): at = 0.125 * Q@K^T -> fp16
//   topk_softmax: exact 171st-largest (2-pass radix, 16-bit keys) -> attn fp16
//   G4' (256x64 dbuf, CH=2, grid (5,4,8)): out = attn @ hWT^T + bias (fp32)
// ---------------------------------------------------------------------------

typedef __attribute__((ext_vector_type(8))) _Float16 half8;
typedef __attribute__((ext_vector_type(4))) float f32x4;

// ---- stage a (nrow16*16) x 32 fp16 tile into LDS, K-chunk XOR-swizzled -----
// LDS slot s of row r holds global chunk s ^ ((r>>1)&3). global_load_lds dest
// is the mandatory uniform base + lane*16B; only the global SOURCE is
// permuted (stays 64B coalesced).
__device__ __forceinline__ void stage_tile(const __half* g, __half* lds,
                                           int nrow16, int ld, int wave, int lane) {
    const int r = lane >> 2;
    const int c = ((lane & 3) ^ ((lane >> 3) & 3)) * 8;  // swizzled chunk
    for (int i = wave; i < nrow16; i += 4) {
        const __half* src = g + (long)(i * 16 + r) * ld + c;
        __builtin_amdgcn_global_load_lds(
            (const __attribute__((address_space(1))) unsigned int*)src,
            (__attribute__((address_space(3))) unsigned int*)(lds + i * 512),
            16, 0, 0);
    }
}

// ---------------------------------------------------------------------------
// NT fp16 MFMA GEMM, double-buffered, CH 32-chunks per barrier round
// (BK = 32*CH). 256 threads = 4 waves in WM x WN grid; wave tile 64x64.
// Buffer layout: [A c0][A c1]..[B c0][B c1].. each sub-tile in the proven
// swizzled 32-wide layout.
// EPI: 1 = +bqk, deinterleave -> Q fp16, K fp16   [G1']
//      2 = fp16 store                              [hWT]
//      3 = fp32 store + bias, batch-strided        [G4' -> out]
//      4 = fp16 store (alpha)                      [G2 -> at]
// ---------------------------------------------------------------------------
template <int WM, int WN, int EPI, int CH>
__global__ __launch_bounds__(256) void gemm_nt(
    const __half* __restrict__ A, const __half* __restrict__ B,
    void* __restrict__ C, void* __restrict__ C2,
    const float* __restrict__ bias,
    int K, int lda, int ldb, int ldc,
    long sA, long sB, long sC, float alpha)
{
    constexpr int BM = WM * 64;
    constexpr int BN = WN * 64;
    constexpr int A_EL = BM * 32;
    constexpr int B_EL = BN * 32;
    constexpr int BUF = (A_EL + B_EL) * CH;
    __shared__ __half smem[2 * BUF];

    const int tid  = threadIdx.x;
    const int lane = tid & 63;
    const int wave = tid >> 6;
    const int wm   = wave / WN;
    const int wn   = wave % WN;
    const int bz   = blockIdx.z;

    const __half* Ab = A + bz * sA + (long)blockIdx.y * BM * lda;
    const __half* Bb = B + bz * sB + (long)blockIdx.x * BN * ldb;

    f32x4 acc[4][4];
    #pragma unroll
    for (int i = 0; i < 4; ++i)
        #pragma unroll
        for (int j = 0; j < 4; ++j) acc[i][j] = (f32x4){0.f, 0.f, 0.f, 0.f};

    const int lrow = lane & 15;
    const int quad = lane >> 4;
    const int swz = (quad ^ ((lrow >> 1) & 3)) * 8;

    const int nIter = K / (32 * CH);

    #pragma unroll
    for (int c = 0; c < CH; ++c) {
        stage_tile(Ab + c * 32, smem + c * A_EL, BM / 16, lda, wave, lane);
        stage_tile(Bb + c * 32, smem + CH * A_EL + c * B_EL, BN / 16, ldb, wave, lane);
    }

    for (int it = 0; it < nIter; ++it) {
        __syncthreads();
        if (it + 1 < nIter) {
            __half* nb = smem + ((it + 1) & 1) * BUF;
            const int k1 = (it + 1) * 32 * CH;
            #pragma unroll
            for (int c = 0; c < CH; ++c) {
                stage_tile(Ab + k1 + c * 32, nb + c * A_EL, BM / 16, lda, wave, lane);
                stage_tile(Bb + k1 + c * 32, nb + CH * A_EL + c * B_EL, BN / 16, ldb, wave, lane);
            }
        }
        const __half* buf = smem + (it & 1) * BUF;
        #pragma unroll
        for (int c = 0; c < CH; ++c) {
            const __half* pA = buf + c * A_EL + (wm * 64 + lrow) * 32 + swz;
            const __half* pB = buf + CH * A_EL + c * B_EL + (wn * 64 + lrow) * 32 + swz;
            half8 ah[4], bh[4];
            #pragma unroll
            for (int mt = 0; mt < 4; ++mt) ah[mt] = *(const half8*)(pA + mt * 512);
            #pragma unroll
            for (int nt = 0; nt < 4; ++nt) bh[nt] = *(const half8*)(pB + nt * 512);
            #pragma unroll
            for (int mt = 0; mt < 4; ++mt)
                #pragma unroll
                for (int nt = 0; nt < 4; ++nt)
                    acc[mt][nt] = __builtin_amdgcn_mfma_f32_16x16x32_f16(
                        ah[mt], bh[nt], acc[mt][nt], 0, 0, 0);
        }
    }

    const int row_base = blockIdx.y * BM + wm * 64;
    const int col_base = blockIdx.x * BN + wn * 64;
    #pragma unroll
    for (int mt = 0; mt < 4; ++mt)
        #pragma unroll
        for (int nt = 0; nt < 4; ++nt)
            #pragma unroll
            for (int r = 0; r < 4; ++r) {
                const int row = row_base + mt * 16 + quad * 4 + r;
                const int col = col_base + nt * 16 + lrow;
                const float v = acc[mt][nt][r];
                if (EPI == 1) {
                    const float val = v + bias[col];
                    const long idx = (long)row * 320 + (col >> 1);
                    if (col & 1) ((__half*)C2)[idx] = __float2half(val);
                    else         ((__half*)C)[idx]  = __float2half(val);
                } else if (EPI == 2) {
                    ((__half*)C)[(long)row * ldc + col] = __float2half(v);
                } else if (EPI == 3) {
                    ((float*)C)[bz * sC + (long)row * ldc + col] = v + bias[col];
                } else {  // EPI == 4
                    ((__half*)C)[bz * sC + (long)row * ldc + col] =
                        __float2half(alpha * v);
                }
            }
}

// ---------------------------------------------------------------------------
// 128x128 NT fp16 dbuf GEMM body with runtime bx/by (R10-proven), K=320.
// EPI 1: +bqk, deinterleave -> Q,K fp16.  EPI 2: fp16 store (hWT, ldc=8192).
// ---------------------------------------------------------------------------
template <int EPI>
__device__ __forceinline__ void gemm_body(
    const __half* __restrict__ A, const __half* __restrict__ B,
    void* __restrict__ C, void* __restrict__ C2, const float* __restrict__ bias,
    int lda, int ldb, int ldc, int bx, int by, __half* smem)
{
    constexpr int BUF = 8192;
    const int tid  = threadIdx.x;
    const int lane = tid & 63;
    const int wave = tid >> 6;
    const int wm   = wave >> 1;
    const int wn   = wave & 1;

    const __half* Ab = A + (long)by * 128 * lda;
    const __half* Bb = B + (long)bx * 128 * ldb;

    f32x4 acc[4][4];
    #pragma unroll
    for (int i = 0; i < 4; ++i)
        #pragma unroll
        for (int j = 0; j < 4; ++j) acc[i][j] = (f32x4){0.f, 0.f, 0.f, 0.f};

    const int lrow = lane & 15;
    const int quad = lane >> 4;
    const int swz = (quad ^ ((lrow >> 1) & 3)) * 8;

    stage_tile(Ab, smem, 8, lda, wave, lane);
    stage_tile(Bb, smem + 4096, 8, ldb, wave, lane);

    for (int it = 0; it < 10; ++it) {
        __syncthreads();
        if (it + 1 < 10) {
            __half* nb = smem + ((it + 1) & 1) * BUF;
            stage_tile(Ab + (it + 1) * 32, nb, 8, lda, wave, lane);
            stage_tile(Bb + (it + 1) * 32, nb + 4096, 8, ldb, wave, lane);
        }
        const __half* buf = smem + (it & 1) * BUF;
        const __half* pA = buf + (wm * 64 + lrow) * 32 + swz;
        const __half* pB = buf + 4096 + (wn * 64 + lrow) * 32 + swz;
        half8 ah[4], bh[4];
        #pragma unroll
        for (int mt = 0; mt < 4; ++mt) ah[mt] = *(const half8*)(pA + mt * 512);
        #pragma unroll
        for (int nt = 0; nt < 4; ++nt) bh[nt] = *(const half8*)(pB + nt * 512);
        #pragma unroll
        for (int mt = 0; mt < 4; ++mt)
            #pragma unroll
            for (int nt = 0; nt < 4; ++nt)
                acc[mt][nt] = __builtin_amdgcn_mfma_f32_16x16x32_f16(
                    ah[mt], bh[nt], acc[mt][nt], 0, 0, 0);
    }

    const int row_base = by * 128 + wm * 64;
    const int col_base = bx * 128 + wn * 64;
    #pragma unroll
    for (int mt = 0; mt < 4; ++mt)
        #pragma unroll
        for (int nt = 0; nt < 4; ++nt)
            #pragma unroll
            for (int r = 0; r < 4; ++r) {
                const int row = row_base + mt * 16 + quad * 4 + r;
                const int col = col_base + nt * 16 + lrow;
                const float v = acc[mt][nt][r];
                if (EPI == 1) {
                    const float val = v + bias[col];
                    const long idx = (long)row * 320 + (col >> 1);
                    if (col & 1) ((__half*)C2)[idx] = __float2half(val);
                    else         ((__half*)C)[idx]  = __float2half(val);
                } else {
                    ((__half*)C)[(long)row * ldc + col] = __float2half(v);
                }
            }
}

// ---- combined: blocks 0..191 do hWT (64x3 tiles); 192..511 do G1' (5x64) ---
__global__ __launch_bounds__(256) void g1_combined(
    const __half* __restrict__ h16, const __half* __restrict__ wTp,
    const __half* __restrict__ WqkT, __half* __restrict__ hWT,
    __half* __restrict__ Q, __half* __restrict__ Kb,
    const float* __restrict__ bqk)
{
    __shared__ __half smem[2 * 8192];
    const int bx = blockIdx.x;
    if (bx < 192) {
        gemm_body<2>(wTp, h16, hWT, nullptr, nullptr,
                     320, 320, 8192, bx % 64, bx / 64, smem);
    } else {
        const int b = bx - 192;
        gemm_body<1>(h16, WqkT, Q, Kb, bqk,
                     320, 320, 320, b % 5, b / 5, smem);
    }
}

// ---- fused prep: h->fp16 (blocks 0..2559) | Wqk^T | weight^T --------------
__global__ __launch_bounds__(256) void prep_all(
    const float* __restrict__ h, ushort4* __restrict__ h16,
    const float* __restrict__ Wqk, __half* __restrict__ WqkT,
    const float* __restrict__ weight, __half* __restrict__ wTp)
{
    const int bx = blockIdx.x;
    if (bx < 2560) {
        const int i = bx * 256 + threadIdx.x;
        const float4 v = ((const float4*)h)[i];
        ushort4 o;
        o.x = __half_as_ushort(__float2half(v.x));
        o.y = __half_as_ushort(__float2half(v.y));
        o.z = __half_as_ushort(__float2half(v.z));
        o.w = __half_as_ushort(__float2half(v.w));
        h16[i] = o;
        return;
    }
    __shared__ float t[32][33];
    const float* src;
    __half* dst;
    int ldS, ldT, c0, r0;
    if (bx < 2760) {
        const int b = bx - 2560;
        src = Wqk; dst = WqkT; ldS = 640; ldT = 320;
        c0 = (b % 20) * 32; r0 = (b / 20) * 32;
    } else {
        const int b = bx - 2760;
        src = weight; dst = wTp; ldS = 320; ldT = 320;
        c0 = (b % 10) * 32; r0 = (b / 10) * 32;
    }
    const int lx = threadIdx.x & 31, ly = threadIdx.x >> 5;
    #pragma unroll
    for (int i = 0; i < 4; ++i)
        t[ly + 8 * i][lx] = src[(long)(r0 + ly + 8 * i) * ldS + c0 + lx];
    __syncthreads();
    #pragma unroll
    for (int i = 0; i < 4; ++i)
        dst[(long)(c0 + ly + 8 * i) * ldT + r0 + lx] = __float2half(t[lx][ly + 8 * i]);
}

// ---------------------------------------------------------------------------
// Exact 171st-largest per row of 1024 fp16 values: 2-pass radix select on
// 16-bit order-preserving keys. One wave per row (4 rows / block).
// ---------------------------------------------------------------------------
__global__ __launch_bounds__(256) void topk_softmax(const __half* __restrict__ at,
                                                    __half* __restrict__ attn)
{
    __shared__ int hist[4][256];
    const int lane = threadIdx.x & 63;
    const int wave = threadIdx.x >> 6;
    const long row = (long)blockIdx.x * 4 + wave;

    unsigned short vs[16];
    {
        const uint4* p = (const uint4*)(at + row * 1024 + lane * 16);
        *(uint4*)&vs[0] = p[0];
        *(uint4*)&vs[8] = p[1];
    }

    unsigned key[16];
    #pragma unroll
    for (int i = 0; i < 16; ++i) {
        const unsigned u = vs[i];
        key[i] = (u & 0x8000u) ? ((~u) & 0xFFFFu) : (u | 0x8000u);
    }

    unsigned prefix = 0, pmask = 0;
    int kk = 171;

    #pragma unroll
    for (int pass = 0; pass < 2; ++pass) {
        const int shift = 8 - 8 * pass;
        *(int4*)&hist[wave][lane * 4] = make_int4(0, 0, 0, 0);
        __syncthreads();
        #pragma unroll
        for (int i = 0; i < 16; ++i) {
            if ((key[i] & pmask) == prefix)
                atomicAdd(&hist[wave][(key[i] >> shift) & 255], 1);
        }
        __syncthreads();
        const int4 hh = *(const int4*)&hist[wave][lane * 4];
        const int s = hh.x + hh.y + hh.z + hh.w;
        int suf = s;
        #pragma unroll
        for (int off = 1; off < 64; off <<= 1) {
            const int o = __shfl_down(suf, off);
            if (lane + off < 64) suf += o;
        }
        const int cgt3 = suf - s;
        const int cgt2 = cgt3 + hh.w;
        const int cgt1 = cgt2 + hh.z;
        const int cgt0 = cgt1 + hh.y;
        int pick = 0x7FFFFFFF;
        if (cgt3 < kk && kk <= cgt3 + hh.w) pick = ((4 * lane + 3) << 16) | (kk - cgt3);
        if (cgt2 < kk && kk <= cgt2 + hh.z) pick = ((4 * lane + 2) << 16) | (kk - cgt2);
        if (cgt1 < kk && kk <= cgt1 + hh.y) pick = ((4 * lane + 1) << 16) | (kk - cgt1);
        if (cgt0 < kk && kk <= cgt0 + hh.x) pick = ((4 * lane + 0) << 16) | (kk - cgt0);
        #pragma unroll
        for (int off = 32; off > 0; off >>= 1) pick = min(pick, __shfl_xor(pick, off));
        const unsigned digit = (unsigned)(pick >> 16);
        kk = pick & 0xFFFF;
        prefix |= digit << shift;
        pmask  |= 0xFFu << shift;
        if (pass == 0) __syncthreads();
    }

    const unsigned short tu = (prefix & 0x8000u) ? (unsigned short)(prefix & 0x7FFFu)
                                                 : (unsigned short)((~prefix) & 0xFFFFu);
    const float thr = __half2float(__ushort_as_half(tu));

    float lg[16];
    float mx = -3.4e38f;
    #pragma unroll
    for (int i = 0; i < 16; ++i) {
        const float v = __half2float(__ushort_as_half(vs[i]));
        const float a = (v < thr) ? -1e-7f : v;
        lg[i] = a * (1.0f / 0.3f);
        mx = fmaxf(mx, lg[i]);
    }
    #pragma unroll
    for (int off = 32; off > 0; off >>= 1) mx = fmaxf(mx, __shfl_xor(mx, off));

    float e[16];
    float sum = 0.f;
    #pragma unroll
    for (int i = 0; i < 16; ++i) { e[i] = __expf(lg[i] - mx); sum += e[i]; }
    #pragma unroll
    for (int off = 32; off > 0; off >>= 1) sum += __shfl_xor(sum, off);
    const float inv = 1.0f / sum;

    unsigned short os[16];
    #pragma unroll
    for (int i = 0; i < 16; ++i) os[i] = __half_as_ushort(__float2half(e[i] * inv));
    uint4* q = (uint4*)(attn + row * 1024 + lane * 16);
    q[0] = *(const uint4*)&os[0];
    q[1] = *(const uint4*)&os[8];
}

extern "C" void kernel_launch(void* const* d_in, const int* in_sizes, int n_in,
                              void* d_out, int out_size, void* d_ws, size_t ws_size,
                              hipStream_t stream) {
    (void)in_sizes; (void)n_in; (void)out_size; (void)ws_size;

    const float* h      = (const float*)d_in[0];  // 8x1024x320
    const float* Wqk    = (const float*)d_in[1];  // 320x640
    const float* bqk    = (const float*)d_in[2];  // 640
    const float* weight = (const float*)d_in[3];  // 320x320
    const float* bias   = (const float*)d_in[4];  // 320
    float* out = (float*)d_out;                   // 8192x320

    // workspace layout
    char* p = (char*)d_ws;
    __half* at   = (__half*)p; p += 8388608L * 2;        // 16 MB
    __half* attn = (__half*)p; p += 8388608L * 2;        // 16 MB
    __half* h16  = (__half*)p; p += 2621440L * 2;        // 5 MB
    __half* Q    = (__half*)p; p += 2621440L * 2;        // 5 MB
    __half* Kb   = (__half*)p; p += 2621440L * 2;        // 5 MB
    __half* WqkT = (__half*)p; p += 640L * 320 * 2;      // 400 KB
    __half* wTp  = (__half*)p; p += 384L * 320 * 2;      // padded to 384 rows
    __half* hWT  = (__half*)p; p += 384L * 8192 * 2;     // 6 MB (incl pad rows)

    // --- prep (1 launch): h->fp16, WqkT, wTp ---
    prep_all<<<2860, 256, 0, stream>>>(h, (ushort4*)h16, Wqk, WqkT, weight, wTp);

    // --- combined: hWT (192 blocks) + G1' Q/K (320 blocks) ---
    g1_combined<<<512, 256, 0, stream>>>(h16, wTp, WqkT, hWT, Q, Kb, bqk);

    // --- G2: at = 0.125 * Q@K^T (fp16 out), 128x128 dbuf, BK=32 ---
    gemm_nt<2, 2, 4, 1><<<dim3(8, 8, 8), 256, 0, stream>>>(
        Q, Kb, at, nullptr, nullptr,
        320, 320, 320, 1024, 327680, 327680, 1048576, 0.125f);

    // --- topk + softmax -> attn (fp16); one wave per row ---
    topk_softmax<<<2048, 256, 0, stream>>>(at, attn);

    // --- G4': out = attn @ hWT^T + bias (fp32), 256x64 dbuf, BK=64 ---
    gemm_nt<4, 1, 3, 2><<<dim3(5, 4, 8), 256, 0, stream>>>(
        attn, hWT, out, nullptr, bias,
        1024, 1024, 8192, 320, 1048576, 1024, 327680, 1.0f);
}

// Round 15
// 130.518 us; speedup vs baseline: 1.2265x; 1.0304x over previous
//
#include <hip/hip_runtime.h>
#include <hip/hip_fp16.h>

// ---------------------------------------------------------------------------
// B=8, N=1024, F=320, H=5 (heads collapse: at = (Q·K^T)/8)
// R15: extend R14's BK=64 (CH=2) win to the two remaining 10-round K-loops:
//      G2 and g1_combined (both 512 blocks = 2/CU; LDS 64 KB still allows
//      2 blocks/CU -> occupancy unchanged, barrier rounds 10->5).
//      Accumulation stays in k-order -> numerics bit-identical (0.03125).
// Pipeline:
//   prep_all:    h->fp16 | Wqk^T | weight^T (one launch)
//   g1_combined: [hWT = wTp @ h16^T] + [Q,K = h16 @ WqkT^T + bqk], CH=2
//   G2  (128x128 dbuf, CH=2): at = 0.125 * Q@K^T -> fp16
//   topk_softmax: exact 171st-largest (2-pass radix, 16-bit keys) -> attn fp16
//   G4' (256x64 dbuf, CH=2, grid (5,4,8)): out = attn @ hWT^T + bias (fp32)
// ---------------------------------------------------------------------------

typedef __attribute__((ext_vector_type(8))) _Float16 half8;
typedef __attribute__((ext_vector_type(4))) float f32x4;

// ---- stage a (nrow16*16) x 32 fp16 tile into LDS, K-chunk XOR-swizzled -----
// LDS slot s of row r holds global chunk s ^ ((r>>1)&3). global_load_lds dest
// is the mandatory uniform base + lane*16B; only the global SOURCE is
// permuted (stays 64B coalesced).
__device__ __forceinline__ void stage_tile(const __half* g, __half* lds,
                                           int nrow16, int ld, int wave, int lane) {
    const int r = lane >> 2;
    const int c = ((lane & 3) ^ ((lane >> 3) & 3)) * 8;  // swizzled chunk
    for (int i = wave; i < nrow16; i += 4) {
        const __half* src = g + (long)(i * 16 + r) * ld + c;
        __builtin_amdgcn_global_load_lds(
            (const __attribute__((address_space(1))) unsigned int*)src,
            (__attribute__((address_space(3))) unsigned int*)(lds + i * 512),
            16, 0, 0);
    }
}

// ---------------------------------------------------------------------------
// NT fp16 MFMA GEMM, double-buffered, CH 32-chunks per barrier round
// (BK = 32*CH). 256 threads = 4 waves in WM x WN grid; wave tile 64x64.
// Buffer layout: [A c0][A c1]..[B c0][B c1].. each sub-tile in the proven
// swizzled 32-wide layout. Chunks processed in k-order (bit-identical acc).
// EPI: 1 = +bqk, deinterleave -> Q fp16, K fp16   [G1']
//      2 = fp16 store                              [hWT]
//      3 = fp32 store + bias, batch-strided        [G4' -> out]
//      4 = fp16 store (alpha)                      [G2 -> at]
// ---------------------------------------------------------------------------
template <int WM, int WN, int EPI, int CH>
__global__ __launch_bounds__(256) void gemm_nt(
    const __half* __restrict__ A, const __half* __restrict__ B,
    void* __restrict__ C, void* __restrict__ C2,
    const float* __restrict__ bias,
    int K, int lda, int ldb, int ldc,
    long sA, long sB, long sC, float alpha)
{
    constexpr int BM = WM * 64;
    constexpr int BN = WN * 64;
    constexpr int A_EL = BM * 32;
    constexpr int B_EL = BN * 32;
    constexpr int BUF = (A_EL + B_EL) * CH;
    __shared__ __half smem[2 * BUF];

    const int tid  = threadIdx.x;
    const int lane = tid & 63;
    const int wave = tid >> 6;
    const int wm   = wave / WN;
    const int wn   = wave % WN;
    const int bz   = blockIdx.z;

    const __half* Ab = A + bz * sA + (long)blockIdx.y * BM * lda;
    const __half* Bb = B + bz * sB + (long)blockIdx.x * BN * ldb;

    f32x4 acc[4][4];
    #pragma unroll
    for (int i = 0; i < 4; ++i)
        #pragma unroll
        for (int j = 0; j < 4; ++j) acc[i][j] = (f32x4){0.f, 0.f, 0.f, 0.f};

    const int lrow = lane & 15;
    const int quad = lane >> 4;
    const int swz = (quad ^ ((lrow >> 1) & 3)) * 8;

    const int nIter = K / (32 * CH);

    #pragma unroll
    for (int c = 0; c < CH; ++c) {
        stage_tile(Ab + c * 32, smem + c * A_EL, BM / 16, lda, wave, lane);
        stage_tile(Bb + c * 32, smem + CH * A_EL + c * B_EL, BN / 16, ldb, wave, lane);
    }

    for (int it = 0; it < nIter; ++it) {
        __syncthreads();
        if (it + 1 < nIter) {
            __half* nb = smem + ((it + 1) & 1) * BUF;
            const int k1 = (it + 1) * 32 * CH;
            #pragma unroll
            for (int c = 0; c < CH; ++c) {
                stage_tile(Ab + k1 + c * 32, nb + c * A_EL, BM / 16, lda, wave, lane);
                stage_tile(Bb + k1 + c * 32, nb + CH * A_EL + c * B_EL, BN / 16, ldb, wave, lane);
            }
        }
        const __half* buf = smem + (it & 1) * BUF;
        #pragma unroll
        for (int c = 0; c < CH; ++c) {
            const __half* pA = buf + c * A_EL + (wm * 64 + lrow) * 32 + swz;
            const __half* pB = buf + CH * A_EL + c * B_EL + (wn * 64 + lrow) * 32 + swz;
            half8 ah[4], bh[4];
            #pragma unroll
            for (int mt = 0; mt < 4; ++mt) ah[mt] = *(const half8*)(pA + mt * 512);
            #pragma unroll
            for (int nt = 0; nt < 4; ++nt) bh[nt] = *(const half8*)(pB + nt * 512);
            #pragma unroll
            for (int mt = 0; mt < 4; ++mt)
                #pragma unroll
                for (int nt = 0; nt < 4; ++nt)
                    acc[mt][nt] = __builtin_amdgcn_mfma_f32_16x16x32_f16(
                        ah[mt], bh[nt], acc[mt][nt], 0, 0, 0);
        }
    }

    const int row_base = blockIdx.y * BM + wm * 64;
    const int col_base = blockIdx.x * BN + wn * 64;
    #pragma unroll
    for (int mt = 0; mt < 4; ++mt)
        #pragma unroll
        for (int nt = 0; nt < 4; ++nt)
            #pragma unroll
            for (int r = 0; r < 4; ++r) {
                const int row = row_base + mt * 16 + quad * 4 + r;
                const int col = col_base + nt * 16 + lrow;
                const float v = acc[mt][nt][r];
                if (EPI == 1) {
                    const float val = v + bias[col];
                    const long idx = (long)row * 320 + (col >> 1);
                    if (col & 1) ((__half*)C2)[idx] = __float2half(val);
                    else         ((__half*)C)[idx]  = __float2half(val);
                } else if (EPI == 2) {
                    ((__half*)C)[(long)row * ldc + col] = __float2half(v);
                } else if (EPI == 3) {
                    ((float*)C)[bz * sC + (long)row * ldc + col] = v + bias[col];
                } else {  // EPI == 4
                    ((__half*)C)[bz * sC + (long)row * ldc + col] =
                        __float2half(alpha * v);
                }
            }
}

// ---------------------------------------------------------------------------
// 128x128 NT fp16 dbuf GEMM body, CH=2 (BK=64), runtime bx/by. K=320 -> 5
// barrier rounds. Buffer: [A c0][A c1][B c0][B c1], 4096 halfs each.
// EPI 1: +bqk, deinterleave -> Q,K fp16.  EPI 2: fp16 store (hWT, ldc=8192).
// ---------------------------------------------------------------------------
template <int EPI>
__device__ __forceinline__ void gemm_body(
    const __half* __restrict__ A, const __half* __restrict__ B,
    void* __restrict__ C, void* __restrict__ C2, const float* __restrict__ bias,
    int lda, int ldb, int ldc, int bx, int by, __half* smem)
{
    constexpr int BUF = 16384;  // (4096+4096)*2 halfs
    const int tid  = threadIdx.x;
    const int lane = tid & 63;
    const int wave = tid >> 6;
    const int wm   = wave >> 1;
    const int wn   = wave & 1;

    const __half* Ab = A + (long)by * 128 * lda;
    const __half* Bb = B + (long)bx * 128 * ldb;

    f32x4 acc[4][4];
    #pragma unroll
    for (int i = 0; i < 4; ++i)
        #pragma unroll
        for (int j = 0; j < 4; ++j) acc[i][j] = (f32x4){0.f, 0.f, 0.f, 0.f};

    const int lrow = lane & 15;
    const int quad = lane >> 4;
    const int swz = (quad ^ ((lrow >> 1) & 3)) * 8;

    #pragma unroll
    for (int c = 0; c < 2; ++c) {
        stage_tile(Ab + c * 32, smem + c * 4096, 8, lda, wave, lane);
        stage_tile(Bb + c * 32, smem + 8192 + c * 4096, 8, ldb, wave, lane);
    }

    for (int it = 0; it < 5; ++it) {
        __syncthreads();
        if (it + 1 < 5) {
            __half* nb = smem + ((it + 1) & 1) * BUF;
            const int k1 = (it + 1) * 64;
            #pragma unroll
            for (int c = 0; c < 2; ++c) {
                stage_tile(Ab + k1 + c * 32, nb + c * 4096, 8, lda, wave, lane);
                stage_tile(Bb + k1 + c * 32, nb + 8192 + c * 4096, 8, ldb, wave, lane);
            }
        }
        const __half* buf = smem + (it & 1) * BUF;
        #pragma unroll
        for (int c = 0; c < 2; ++c) {
            const __half* pA = buf + c * 4096 + (wm * 64 + lrow) * 32 + swz;
            const __half* pB = buf + 8192 + c * 4096 + (wn * 64 + lrow) * 32 + swz;
            half8 ah[4], bh[4];
            #pragma unroll
            for (int mt = 0; mt < 4; ++mt) ah[mt] = *(const half8*)(pA + mt * 512);
            #pragma unroll
            for (int nt = 0; nt < 4; ++nt) bh[nt] = *(const half8*)(pB + nt * 512);
            #pragma unroll
            for (int mt = 0; mt < 4; ++mt)
                #pragma unroll
                for (int nt = 0; nt < 4; ++nt)
                    acc[mt][nt] = __builtin_amdgcn_mfma_f32_16x16x32_f16(
                        ah[mt], bh[nt], acc[mt][nt], 0, 0, 0);
        }
    }

    const int row_base = by * 128 + wm * 64;
    const int col_base = bx * 128 + wn * 64;
    #pragma unroll
    for (int mt = 0; mt < 4; ++mt)
        #pragma unroll
        for (int nt = 0; nt < 4; ++nt)
            #pragma unroll
            for (int r = 0; r < 4; ++r) {
                const int row = row_base + mt * 16 + quad * 4 + r;
                const int col = col_base + nt * 16 + lrow;
                const float v = acc[mt][nt][r];
                if (EPI == 1) {
                    const float val = v + bias[col];
                    const long idx = (long)row * 320 + (col >> 1);
                    if (col & 1) ((__half*)C2)[idx] = __float2half(val);
                    else         ((__half*)C)[idx]  = __float2half(val);
                } else {
                    ((__half*)C)[(long)row * ldc + col] = __float2half(v);
                }
            }
}

// ---- combined: blocks 0..191 do hWT (64x3 tiles); 192..511 do G1' (5x64) ---
__global__ __launch_bounds__(256) void g1_combined(
    const __half* __restrict__ h16, const __half* __restrict__ wTp,
    const __half* __restrict__ WqkT, __half* __restrict__ hWT,
    __half* __restrict__ Q, __half* __restrict__ Kb,
    const float* __restrict__ bqk)
{
    __shared__ __half smem[2 * 16384];
    const int bx = blockIdx.x;
    if (bx < 192) {
        gemm_body<2>(wTp, h16, hWT, nullptr, nullptr,
                     320, 320, 8192, bx % 64, bx / 64, smem);
    } else {
        const int b = bx - 192;
        gemm_body<1>(h16, WqkT, Q, Kb, bqk,
                     320, 320, 320, b % 5, b / 5, smem);
    }
}

// ---- fused prep: h->fp16 (blocks 0..2559) | Wqk^T | weight^T --------------
__global__ __launch_bounds__(256) void prep_all(
    const float* __restrict__ h, ushort4* __restrict__ h16,
    const float* __restrict__ Wqk, __half* __restrict__ WqkT,
    const float* __restrict__ weight, __half* __restrict__ wTp)
{
    const int bx = blockIdx.x;
    if (bx < 2560) {
        const int i = bx * 256 + threadIdx.x;
        const float4 v = ((const float4*)h)[i];
        ushort4 o;
        o.x = __half_as_ushort(__float2half(v.x));
        o.y = __half_as_ushort(__float2half(v.y));
        o.z = __half_as_ushort(__float2half(v.z));
        o.w = __half_as_ushort(__float2half(v.w));
        h16[i] = o;
        return;
    }
    __shared__ float t[32][33];
    const float* src;
    __half* dst;
    int ldS, ldT, c0, r0;
    if (bx < 2760) {
        const int b = bx - 2560;
        src = Wqk; dst = WqkT; ldS = 640; ldT = 320;
        c0 = (b % 20) * 32; r0 = (b / 20) * 32;
    } else {
        const int b = bx - 2760;
        src = weight; dst = wTp; ldS = 320; ldT = 320;
        c0 = (b % 10) * 32; r0 = (b / 10) * 32;
    }
    const int lx = threadIdx.x & 31, ly = threadIdx.x >> 5;
    #pragma unroll
    for (int i = 0; i < 4; ++i)
        t[ly + 8 * i][lx] = src[(long)(r0 + ly + 8 * i) * ldS + c0 + lx];
    __syncthreads();
    #pragma unroll
    for (int i = 0; i < 4; ++i)
        dst[(long)(c0 + ly + 8 * i) * ldT + r0 + lx] = __float2half(t[lx][ly + 8 * i]);
}

// ---------------------------------------------------------------------------
// Exact 171st-largest per row of 1024 fp16 values: 2-pass radix select on
// 16-bit order-preserving keys. One wave per row (4 rows / block).
// ---------------------------------------------------------------------------
__global__ __launch_bounds__(256) void topk_softmax(const __half* __restrict__ at,
                                                    __half* __restrict__ attn)
{
    __shared__ int hist[4][256];
    const int lane = threadIdx.x & 63;
    const int wave = threadIdx.x >> 6;
    const long row = (long)blockIdx.x * 4 + wave;

    unsigned short vs[16];
    {
        const uint4* p = (const uint4*)(at + row * 1024 + lane * 16);
        *(uint4*)&vs[0] = p[0];
        *(uint4*)&vs[8] = p[1];
    }

    unsigned key[16];
    #pragma unroll
    for (int i = 0; i < 16; ++i) {
        const unsigned u = vs[i];
        key[i] = (u & 0x8000u) ? ((~u) & 0xFFFFu) : (u | 0x8000u);
    }

    unsigned prefix = 0, pmask = 0;
    int kk = 171;

    #pragma unroll
    for (int pass = 0; pass < 2; ++pass) {
        const int shift = 8 - 8 * pass;
        *(int4*)&hist[wave][lane * 4] = make_int4(0, 0, 0, 0);
        __syncthreads();
        #pragma unroll
        for (int i = 0; i < 16; ++i) {
            if ((key[i] & pmask) == prefix)
                atomicAdd(&hist[wave][(key[i] >> shift) & 255], 1);
        }
        __syncthreads();
        const int4 hh = *(const int4*)&hist[wave][lane * 4];
        const int s = hh.x + hh.y + hh.z + hh.w;
        int suf = s;
        #pragma unroll
        for (int off = 1; off < 64; off <<= 1) {
            const int o = __shfl_down(suf, off);
            if (lane + off < 64) suf += o;
        }
        const int cgt3 = suf - s;
        const int cgt2 = cgt3 + hh.w;
        const int cgt1 = cgt2 + hh.z;
        const int cgt0 = cgt1 + hh.y;
        int pick = 0x7FFFFFFF;
        if (cgt3 < kk && kk <= cgt3 + hh.w) pick = ((4 * lane + 3) << 16) | (kk - cgt3);
        if (cgt2 < kk && kk <= cgt2 + hh.z) pick = ((4 * lane + 2) << 16) | (kk - cgt2);
        if (cgt1 < kk && kk <= cgt1 + hh.y) pick = ((4 * lane + 1) << 16) | (kk - cgt1);
        if (cgt0 < kk && kk <= cgt0 + hh.x) pick = ((4 * lane + 0) << 16) | (kk - cgt0);
        #pragma unroll
        for (int off = 32; off > 0; off >>= 1) pick = min(pick, __shfl_xor(pick, off));
        const unsigned digit = (unsigned)(pick >> 16);
        kk = pick & 0xFFFF;
        prefix |= digit << shift;
        pmask  |= 0xFFu << shift;
        if (pass == 0) __syncthreads();
    }

    const unsigned short tu = (prefix & 0x8000u) ? (unsigned short)(prefix & 0x7FFFu)
                                                 : (unsigned short)((~prefix) & 0xFFFFu);
    const float thr = __half2float(__ushort_as_half(tu));

    float lg[16];
    float mx = -3.4e38f;
    #pragma unroll
    for (int i = 0; i < 16; ++i) {
        const float v = __half2float(__ushort_as_half(vs[i]));
        const float a = (v < thr) ? -1e-7f : v;
        lg[i] = a * (1.0f / 0.3f);
        mx = fmaxf(mx, lg[i]);
    }
    #pragma unroll
    for (int off = 32; off > 0; off >>= 1) mx = fmaxf(mx, __shfl_xor(mx, off));

    float e[16];
    float sum = 0.f;
    #pragma unroll
    for (int i = 0; i < 16; ++i) { e[i] = __expf(lg[i] - mx); sum += e[i]; }
    #pragma unroll
    for (int off = 32; off > 0; off >>= 1) sum += __shfl_xor(sum, off);
    const float inv = 1.0f / sum;

    unsigned short os[16];
    #pragma unroll
    for (int i = 0; i < 16; ++i) os[i] = __half_as_ushort(__float2half(e[i] * inv));
    uint4* q = (uint4*)(attn + row * 1024 + lane * 16);
    q[0] = *(const uint4*)&os[0];
    q[1] = *(const uint4*)&os[8];
}

extern "C" void kernel_launch(void* const* d_in, const int* in_sizes, int n_in,
                              void* d_out, int out_size, void* d_ws, size_t ws_size,
                              hipStream_t stream) {
    (void)in_sizes; (void)n_in; (void)out_size; (void)ws_size;

    const float* h      = (const float*)d_in[0];  // 8x1024x320
    const float* Wqk    = (const float*)d_in[1];  // 320x640
    const float* bqk    = (const float*)d_in[2];  // 640
    const float* weight = (const float*)d_in[3];  // 320x320
    const float* bias   = (const float*)d_in[4];  // 320
    float* out = (float*)d_out;                   // 8192x320

    // workspace layout
    char* p = (char*)d_ws;
    __half* at   = (__half*)p; p += 8388608L * 2;        // 16 MB
    __half* attn = (__half*)p; p += 8388608L * 2;        // 16 MB
    __half* h16  = (__half*)p; p += 2621440L * 2;        // 5 MB
    __half* Q    = (__half*)p; p += 2621440L * 2;        // 5 MB
    __half* Kb   = (__half*)p; p += 2621440L * 2;        // 5 MB
    __half* WqkT = (__half*)p; p += 640L * 320 * 2;      // 400 KB
    __half* wTp  = (__half*)p; p += 384L * 320 * 2;      // padded to 384 rows
    __half* hWT  = (__half*)p; p += 384L * 8192 * 2;     // 6 MB (incl pad rows)

    // --- prep (1 launch): h->fp16, WqkT, wTp ---
    prep_all<<<2860, 256, 0, stream>>>(h, (ushort4*)h16, Wqk, WqkT, weight, wTp);

    // --- combined: hWT (192 blocks) + G1' Q/K (320 blocks), BK=64 ---
    g1_combined<<<512, 256, 0, stream>>>(h16, wTp, WqkT, hWT, Q, Kb, bqk);

    // --- G2: at = 0.125 * Q@K^T (fp16 out), 128x128 dbuf, BK=64 ---
    gemm_nt<2, 2, 4, 2><<<dim3(8, 8, 8), 256, 0, stream>>>(
        Q, Kb, at, nullptr, nullptr,
        320, 320, 320, 1024, 327680, 327680, 1048576, 0.125f);

    // --- topk + softmax -> attn (fp16); one wave per row ---
    topk_softmax<<<2048, 256, 0, stream>>>(at, attn);

    // --- G4': out = attn @ hWT^T + bias (fp32), 256x64 dbuf, BK=64 ---
    gemm_nt<4, 1, 3, 2><<<dim3(5, 4, 8), 256, 0, stream>>>(
        attn, hWT, out, nullptr, bias,
        1024, 1024, 8192, 320, 1048576, 1024, 327680, 1.0f);
}